// Round 4
// baseline (9665.400 us; speedup 1.0000x reference)
//
#include <hip/hip_runtime.h>

#define NB 16
#define NN 2048
#define G  64                 // blocks per batch; each block owns 32 rows (4 tiles of 8)
#define ITERS 100

typedef float v2f __attribute__((ext_vector_type(2)));

static constexpr float INV_N = 1.0f / (float)NN;
static constexpr float NEG_INV_EPS = -10.0f;     // -1/eps, eps = 0.1

__device__ __forceinline__ float fastrcp(float x) { return __builtin_amdgcn_rcpf(x); }

// decode 4 packed fp8-e4m3 bytes -> 4 floats (HW v_cvt_pk_f32_fp8)
__device__ __forceinline__ void dec4(unsigned int u, float& f0, float& f1, float& f2, float& f3) {
    v2f lo = __builtin_amdgcn_cvt_pk_f32_fp8((int)u, false);
    v2f hi = __builtin_amdgcn_cvt_pk_f32_fp8((int)u, true);
    f0 = lo[0]; f1 = lo[1]; f2 = hi[0]; f3 = hi[1];
}

// ------------------------------------------------- build K8 = fp8(K * s_row), INVS = 1/s_row (pow2)
__global__ __launch_bounds__(256) void build_K(const float* __restrict__ x,
                                               const float* __restrict__ y,
                                               unsigned char* __restrict__ K8,
                                               float* __restrict__ INVS) {
    const int n = blockIdx.x, b = blockIdx.y, tid = threadIdx.x;
    const int w = tid >> 6, l = tid & 63;
    const float* xb = x + (size_t)b * 3 * NN;
    const float* yb = y + (size_t)b * 3 * NN;
    const float x0 = xb[n], x1 = xb[NN + n], x2 = xb[2 * NN + n];
    const float xs = x0 * x0 + x1 * x1 + x2 * x2;
    const int m0 = tid * 8;

    const float4 a0 = *(const float4*)(yb + m0);
    const float4 a1 = *(const float4*)(yb + m0 + 4);
    const float4 b0 = *(const float4*)(yb + NN + m0);
    const float4 b1 = *(const float4*)(yb + NN + m0 + 4);
    const float4 c0 = *(const float4*)(yb + 2 * NN + m0);
    const float4 c1 = *(const float4*)(yb + 2 * NN + m0 + 4);
    const float yy0[8] = {a0.x, a0.y, a0.z, a0.w, a1.x, a1.y, a1.z, a1.w};
    const float yy1[8] = {b0.x, b0.y, b0.z, b0.w, b1.x, b1.y, b1.z, b1.w};
    const float yy2[8] = {c0.x, c0.y, c0.z, c0.w, c1.x, c1.y, c1.z, c1.w};

    float k[8];
#pragma unroll
    for (int j = 0; j < 8; ++j) {
        const float ys  = yy0[j] * yy0[j] + yy1[j] * yy1[j] + yy2[j] * yy2[j];
        const float dot = x0 * yy0[j] + x1 * yy1[j] + x2 * yy2[j];
        const float C   = fmaxf(xs + ys - 2.0f * dot, 0.0f);
        k[j] = __expf(NEG_INV_EPS * C);
    }

    // row max -> pow2 scale
    float mx = fmaxf(fmaxf(fmaxf(k[0], k[1]), fmaxf(k[2], k[3])),
                     fmaxf(fmaxf(k[4], k[5]), fmaxf(k[6], k[7])));
#pragma unroll
    for (int off = 32; off > 0; off >>= 1) mx = fmaxf(mx, __shfl_xor(mx, off, 64));
    __shared__ float red[4];
    if (l == 0) red[w] = mx;
    __syncthreads();
    mx = fmaxf(fmaxf(red[0], red[1]), fmaxf(red[2], red[3]));
    mx = fmaxf(mx, 1e-30f);
    const int e = (int)((__float_as_uint(mx) >> 23) & 0xffu) - 127;   // mx in [2^e, 2^{e+1})
    const float sc = __uint_as_float((unsigned)(127 - e) << 23);      // scaled max in [1,2)
    if (tid == 0) INVS[b * NN + n] = __uint_as_float((unsigned)(127 + e) << 23);

    int p0 = __builtin_amdgcn_cvt_pk_fp8_f32(k[0] * sc, k[1] * sc, 0, false);
    p0     = __builtin_amdgcn_cvt_pk_fp8_f32(k[2] * sc, k[3] * sc, p0, true);
    int p1 = __builtin_amdgcn_cvt_pk_fp8_f32(k[4] * sc, k[5] * sc, 0, false);
    p1     = __builtin_amdgcn_cvt_pk_fp8_f32(k[6] * sc, k[7] * sc, p1, true);
    uint2 pk; pk.x = (unsigned)p0; pk.y = (unsigned)p1;
    *(uint2*)(K8 + ((size_t)(b * NN + n)) * NN + m0) = pk;
}

// ------------------------------------------------- reduce: v[m] = inv_n/(sum_g PART[g][m] + 1e-8)
__global__ __launch_bounds__(256) void reduce_v(const float* __restrict__ PART,
                                                float* __restrict__ VV) {
    const int t = blockIdx.x * 256 + threadIdx.x;         // t in [0, NB*NN)
    const int b = t >> 11, m = t & (NN - 1);
    const float* p = PART + (size_t)(b * G) * NN + m;
    float s = 0.0f;
#pragma unroll 8
    for (int g = 0; g < G; ++g) s += p[(size_t)g * NN];
    VV[t] = INV_N * fastrcp(s + 1e-8f);
}

// ------------------------------------------------- fused pass (single sweep of K8):
// Each wave owns columns [w*512, (w+1)*512) for ALL 32 rows of the block.
//   phase A (per 8-row tile): wave-slice dots -> lds_d fold -> uw[r] = u[r]*invs[r]
//   phase B (same tile, K bytes still in regs): acc[j] += K8 * uw[r]
// Column partials are wave-disjoint -> direct PART store, no LDS fold.
__global__ __launch_bounds__(256) void fused_pass(const unsigned char* __restrict__ K8,
                                                  const float* __restrict__ VV,
                                                  const float* __restrict__ INVS,
                                                  float* __restrict__ u_out,
                                                  float* __restrict__ PART,
                                                  int first) {
    const int g = blockIdx.x, b = blockIdx.y, tid = threadIdx.x;
    const int w = tid >> 6, l = tid & 63;
    const int col0 = w * 512 + l * 8;                     // this lane's 8 columns
    const int row0 = g * 32;

    __shared__ float lds_d[2][4][8];                      // [parity][wave][row-in-tile]

    float v[8];
    if (!first) {
        const float* vb = VV + b * NN + col0;
        const float4 q0 = *(const float4*)(vb);
        const float4 q1 = *(const float4*)(vb + 4);
        v[0] = q0.x; v[1] = q0.y; v[2] = q0.z; v[3] = q0.w;
        v[4] = q1.x; v[5] = q1.y; v[6] = q1.z; v[7] = q1.w;
    }

    float acc[8];
#pragma unroll
    for (int j = 0; j < 8; ++j) acc[j] = 0.0f;

    const unsigned char* Kb = K8 + ((size_t)(b * NN + row0)) * NN + col0;
    const float* invp = INVS + b * NN + row0;

#pragma unroll
    for (int t = 0; t < 4; ++t) {
        const int par = t & 1;
        uint2 kvb[8];
        // ---- phase A: load tile rows, wave-slice dots
#pragma unroll
        for (int r = 0; r < 8; ++r) {
            const uint2 kv = *(const uint2*)(Kb + (size_t)(t * 8 + r) * NN);
            kvb[r] = kv;
            if (!first) {
                float f0, f1, f2, f3, f4, f5, f6, f7;
                dec4(kv.x, f0, f1, f2, f3);
                dec4(kv.y, f4, f5, f6, f7);
                float d = f0 * v[0];
                d = fmaf(f1, v[1], d); d = fmaf(f2, v[2], d); d = fmaf(f3, v[3], d);
                d = fmaf(f4, v[4], d); d = fmaf(f5, v[5], d); d = fmaf(f6, v[6], d);
                d = fmaf(f7, v[7], d);
#pragma unroll
                for (int off = 32; off > 0; off >>= 1) d += __shfl_xor(d, off, 64);
                if (l == 0) lds_d[par][w][r] = d;
            }
        }
        if (!first) __syncthreads();

        // ---- uw[r] for the tile (identical in all waves)
        float uw[8];
#pragma unroll
        for (int r = 0; r < 8; ++r) {
            const float invs = invp[t * 8 + r];
            float u;
            if (first) {
                u = INV_N;
            } else {
                const float s4 = (lds_d[par][0][r] + lds_d[par][1][r]) +
                                 (lds_d[par][2][r] + lds_d[par][3][r]);
                u = INV_N * fastrcp(s4 * invs + 1e-8f);
            }
            const float uwr = u * invs;
            uw[r] = uwr;
            if (w == 0 && l == r) u_out[b * NN + row0 + t * 8 + r] = uwr;
        }

        // ---- phase B: reuse tile bytes from registers
#pragma unroll
        for (int r = 0; r < 8; ++r) {
            float f0, f1, f2, f3, f4, f5, f6, f7;
            dec4(kvb[r].x, f0, f1, f2, f3);
            dec4(kvb[r].y, f4, f5, f6, f7);
            const float uwr = uw[r];
            acc[0] = fmaf(f0, uwr, acc[0]); acc[1] = fmaf(f1, uwr, acc[1]);
            acc[2] = fmaf(f2, uwr, acc[2]); acc[3] = fmaf(f3, uwr, acc[3]);
            acc[4] = fmaf(f4, uwr, acc[4]); acc[5] = fmaf(f5, uwr, acc[5]);
            acc[6] = fmaf(f6, uwr, acc[6]); acc[7] = fmaf(f7, uwr, acc[7]);
        }
    }

    // wave-disjoint column partials: direct store
    float* p = PART + ((size_t)(b * G + g)) * NN + col0;
    *(float4*)(p)     = make_float4(acc[0], acc[1], acc[2], acc[3]);
    *(float4*)(p + 4) = make_float4(acc[4], acc[5], acc[6], acc[7]);
}

// ------------------------------------------------- final: sum uw[n]*K8[n,m]*C[n,m]*v[m] / B
__global__ __launch_bounds__(256) void final_sum(const unsigned char* __restrict__ K8,
                                                 const float* __restrict__ x,
                                                 const float* __restrict__ y,
                                                 const float* __restrict__ VV,
                                                 const float* __restrict__ u_in,   // holds uw = u*invs
                                                 float* __restrict__ out) {
    const int g = blockIdx.x, b = blockIdx.y, tid = threadIdx.x;
    const int w = tid >> 6, l = tid & 63;
    const float* vb = VV + b * NN;

    float v[4][8];
#pragma unroll
    for (int s = 0; s < 4; ++s) {
        const float4 p0 = *(const float4*)(vb + s * 512 + l * 8);
        const float4 p1 = *(const float4*)(vb + s * 512 + l * 8 + 4);
        v[s][0] = p0.x; v[s][1] = p0.y; v[s][2] = p0.z; v[s][3] = p0.w;
        v[s][4] = p1.x; v[s][5] = p1.y; v[s][6] = p1.z; v[s][7] = p1.w;
    }

    const float* xb = x + (size_t)b * 3 * NN;
    const float* yb = y + (size_t)b * 3 * NN;
    float lacc = 0.0f;

    for (int r = 0; r < 8; ++r) {
        const int n = g * 32 + w * 8 + r;
        const float x0 = xb[n], x1 = xb[NN + n], x2 = xb[2 * NN + n];
        const float xs = x0 * x0 + x1 * x1 + x2 * x2;
        const float uwn = u_in[b * NN + n];
        const unsigned char* Kp = K8 + ((size_t)(b * NN + n)) * NN + l * 8;
        float racc = 0.0f;
#pragma unroll
        for (int s = 0; s < 4; ++s) {
            const int m0 = s * 512 + l * 8;
            const uint2 kv = *(const uint2*)(Kp + s * 512);
            float ky[8];
            dec4(kv.x, ky[0], ky[1], ky[2], ky[3]);
            dec4(kv.y, ky[4], ky[5], ky[6], ky[7]);
            const float4 a0 = *(const float4*)(yb + m0);
            const float4 a1 = *(const float4*)(yb + m0 + 4);
            const float4 b0 = *(const float4*)(yb + NN + m0);
            const float4 b1 = *(const float4*)(yb + NN + m0 + 4);
            const float4 c0 = *(const float4*)(yb + 2 * NN + m0);
            const float4 c1 = *(const float4*)(yb + 2 * NN + m0 + 4);
            const float yy0[8] = {a0.x, a0.y, a0.z, a0.w, a1.x, a1.y, a1.z, a1.w};
            const float yy1[8] = {b0.x, b0.y, b0.z, b0.w, b1.x, b1.y, b1.z, b1.w};
            const float yy2[8] = {c0.x, c0.y, c0.z, c0.w, c1.x, c1.y, c1.z, c1.w};
#pragma unroll
            for (int j = 0; j < 8; ++j) {
                const float ys  = yy0[j] * yy0[j] + yy1[j] * yy1[j] + yy2[j] * yy2[j];
                const float dot = x0 * yy0[j] + x1 * yy1[j] + x2 * yy2[j];
                const float C   = fmaxf(xs + ys - 2.0f * dot, 0.0f);
                racc = fmaf(ky[j] * C, v[s][j], racc);
            }
        }
        lacc = fmaf(uwn, racc, lacc);   // uwn uniform per row: defer lane-reduction
    }
#pragma unroll
    for (int off = 32; off > 0; off >>= 1) lacc += __shfl_xor(lacc, off, 64);
    __shared__ float red[4];
    if (l == 0) red[w] = lacc;
    __syncthreads();
    if (tid == 0) atomicAdd(out, (red[0] + red[1] + red[2] + red[3]) * (1.0f / (float)NB));
}

extern "C" void kernel_launch(void* const* d_in, const int* in_sizes, int n_in,
                              void* d_out, int out_size, void* d_ws, size_t ws_size,
                              hipStream_t stream) {
    const float* x = (const float*)d_in[0];
    const float* y = (const float*)d_in[1];
    float* out = (float*)d_out;
    char* ws = (char*)d_ws;

    unsigned char* K8 = (unsigned char*)ws;                  // 16*2048*2048 = 67,108,864 B
    const size_t KBYTES = (size_t)NB * NN * NN;
    float* PART = (float*)(ws + KBYTES);                     // 16*64*2048*4 = 8 MiB
    const size_t PARTN = (size_t)NB * G * NN;
    float* VV   = PART + PARTN;                              // v vector, 128 KiB
    float* ub   = VV + (size_t)NB * NN;                      // uw vector, 128 KiB

    float* INVS = ub + (size_t)NB * NN;                      // per-row 1/scale, 128 KiB

    hipMemsetAsync(out, 0, sizeof(float), stream);

    build_K<<<dim3(NN, NB), 256, 0, stream>>>(x, y, K8, INVS);

    // iteration 0 half-step: PART <- K^T u0 (u0 = inv_n), phase A skipped
    fused_pass<<<dim3(G, NB), 256, 0, stream>>>(K8, VV, INVS, ub, PART, 1);
    for (int i = 0; i < ITERS; ++i) {
        reduce_v<<<dim3(NB * NN / 256), 256, 0, stream>>>(PART, VV);               // v_k
        fused_pass<<<dim3(G, NB), 256, 0, stream>>>(K8, VV, INVS, ub, PART, 0);    // u_k, PART
    }
    // ub = uw_100, VV = v_100
    final_sum<<<dim3(G, NB), 256, 0, stream>>>(K8, x, y, VV, ub, out);
}

// Round 5
// 2476.675 us; speedup vs baseline: 3.9026x; 3.9026x over previous
//
#include <hip/hip_runtime.h>

#define NB 16
#define NN 2048
#define G  64                 // blocks per batch; block owns 32 rows (4 waves x 8 rows)
#define ITERS 100

typedef float v2f __attribute__((ext_vector_type(2)));

static constexpr float INV_N = 1.0f / (float)NN;
static constexpr float NEG_INV_EPS = -10.0f;     // -1/eps, eps = 0.1

__device__ __forceinline__ float fastrcp(float x) { return __builtin_amdgcn_rcpf(x); }

// decode 4 packed fp8-e4m3 bytes -> 4 floats (HW v_cvt_pk_f32_fp8)
__device__ __forceinline__ void dec4(unsigned int u, float& f0, float& f1, float& f2, float& f3) {
    v2f lo = __builtin_amdgcn_cvt_pk_f32_fp8((int)u, false);
    v2f hi = __builtin_amdgcn_cvt_pk_f32_fp8((int)u, true);
    f0 = lo[0]; f1 = lo[1]; f2 = hi[0]; f3 = hi[1];
}

// ------------------------------------------------- build K8 = fp8(K * s_row), INVS = 1/s_row (pow2)
__global__ __launch_bounds__(256) void build_K(const float* __restrict__ x,
                                               const float* __restrict__ y,
                                               unsigned char* __restrict__ K8,
                                               float* __restrict__ INVS) {
    const int n = blockIdx.x, b = blockIdx.y, tid = threadIdx.x;
    const int w = tid >> 6, l = tid & 63;
    const float* xb = x + (size_t)b * 3 * NN;
    const float* yb = y + (size_t)b * 3 * NN;
    const float x0 = xb[n], x1 = xb[NN + n], x2 = xb[2 * NN + n];
    const float xs = x0 * x0 + x1 * x1 + x2 * x2;
    const int m0 = tid * 8;

    const float4 a0 = *(const float4*)(yb + m0);
    const float4 a1 = *(const float4*)(yb + m0 + 4);
    const float4 b0 = *(const float4*)(yb + NN + m0);
    const float4 b1 = *(const float4*)(yb + NN + m0 + 4);
    const float4 c0 = *(const float4*)(yb + 2 * NN + m0);
    const float4 c1 = *(const float4*)(yb + 2 * NN + m0 + 4);
    const float yy0[8] = {a0.x, a0.y, a0.z, a0.w, a1.x, a1.y, a1.z, a1.w};
    const float yy1[8] = {b0.x, b0.y, b0.z, b0.w, b1.x, b1.y, b1.z, b1.w};
    const float yy2[8] = {c0.x, c0.y, c0.z, c0.w, c1.x, c1.y, c1.z, c1.w};

    float k[8];
#pragma unroll
    for (int j = 0; j < 8; ++j) {
        const float ys  = yy0[j] * yy0[j] + yy1[j] * yy1[j] + yy2[j] * yy2[j];
        const float dot = x0 * yy0[j] + x1 * yy1[j] + x2 * yy2[j];
        const float C   = fmaxf(xs + ys - 2.0f * dot, 0.0f);
        k[j] = __expf(NEG_INV_EPS * C);
    }

    // row max -> pow2 scale
    float mx = fmaxf(fmaxf(fmaxf(k[0], k[1]), fmaxf(k[2], k[3])),
                     fmaxf(fmaxf(k[4], k[5]), fmaxf(k[6], k[7])));
#pragma unroll
    for (int off = 32; off > 0; off >>= 1) mx = fmaxf(mx, __shfl_xor(mx, off, 64));
    __shared__ float red[4];
    if (l == 0) red[w] = mx;
    __syncthreads();
    mx = fmaxf(fmaxf(red[0], red[1]), fmaxf(red[2], red[3]));
    mx = fmaxf(mx, 1e-30f);
    const int e = (int)((__float_as_uint(mx) >> 23) & 0xffu) - 127;   // mx in [2^e, 2^{e+1})
    const float sc = __uint_as_float((unsigned)(127 - e) << 23);      // scaled max in [1,2)
    if (tid == 0) INVS[b * NN + n] = __uint_as_float((unsigned)(127 + e) << 23);

    int p0 = __builtin_amdgcn_cvt_pk_fp8_f32(k[0] * sc, k[1] * sc, 0, false);
    p0     = __builtin_amdgcn_cvt_pk_fp8_f32(k[2] * sc, k[3] * sc, p0, true);
    int p1 = __builtin_amdgcn_cvt_pk_fp8_f32(k[4] * sc, k[5] * sc, 0, false);
    p1     = __builtin_amdgcn_cvt_pk_fp8_f32(k[6] * sc, k[7] * sc, p1, true);
    uint2 pk; pk.x = (unsigned)p0; pk.y = (unsigned)p1;
    *(uint2*)(K8 + ((size_t)(b * NN + n)) * NN + m0) = pk;
}

// ------------------------------------------------- reduce: v[m] = inv_n/(sum_g PART[g][m] + 1e-8)
__global__ __launch_bounds__(256) void reduce_v(const float* __restrict__ PART,
                                                float* __restrict__ VV) {
    const int t = blockIdx.x * 256 + threadIdx.x;         // t in [0, NB*NN)
    const int b = t >> 11, m = t & (NN - 1);
    const float* p = PART + (size_t)(b * G) * NN + m;
    float s = 0.0f;
#pragma unroll 8
    for (int g = 0; g < G; ++g) s += p[(size_t)g * NN];
    VV[t] = INV_N * fastrcp(s + 1e-8f);
}

// ------------------------------------------------- fused pass (single sweep of K8), round-2 structure:
// wave w owns rows g*32+w*8 .. +7 entirely; lane l owns columns {s*512 + l*8 + j}.
//   per row: load 4x uint2 (row bytes stay in regs), dot via decode+FMA, 6-shuffle reduce,
//            u = inv_n/(d*invs+1e-8), uw = u*invs, acc[s][j] += K8*uw (re-decode from regs)
//   epilogue: 4-wave LDS fold -> PART (one partial per block)
__global__ __launch_bounds__(256) void fused_pass(const unsigned char* __restrict__ K8,
                                                  const float* __restrict__ VV,
                                                  const float* __restrict__ INVS,
                                                  float* __restrict__ u_out,
                                                  float* __restrict__ PART,
                                                  int first) {
    const int g = blockIdx.x, b = blockIdx.y, tid = threadIdx.x;
    const int w = tid >> 6, l = tid & 63;

    float v[4][8];
    if (!first) {
        const float* vb = VV + b * NN;
#pragma unroll
        for (int s = 0; s < 4; ++s) {
            const float4 p0 = *(const float4*)(vb + s * 512 + l * 8);
            const float4 p1 = *(const float4*)(vb + s * 512 + l * 8 + 4);
            v[s][0] = p0.x; v[s][1] = p0.y; v[s][2] = p0.z; v[s][3] = p0.w;
            v[s][4] = p1.x; v[s][5] = p1.y; v[s][6] = p1.z; v[s][7] = p1.w;
        }
    }

    float acc[4][8];
#pragma unroll
    for (int s = 0; s < 4; ++s)
#pragma unroll
        for (int j = 0; j < 8; ++j) acc[s][j] = 0.0f;

    const int row0 = g * 32 + w * 8;
    const unsigned char* Kb = K8 + ((size_t)(b * NN + row0)) * NN + l * 8;
    const float* invp = INVS + b * NN + row0;

#pragma unroll 2
    for (int r = 0; r < 8; ++r) {
        uint2 kv[4];
#pragma unroll
        for (int s = 0; s < 4; ++s) kv[s] = *(const uint2*)(Kb + (size_t)r * NN + s * 512);
        const float invs = invp[r];

        float u;
        if (first) {
            u = INV_N;
        } else {
            float d0 = 0, d1 = 0, d2 = 0, d3 = 0, d4 = 0, d5 = 0, d6 = 0, d7 = 0;
#pragma unroll
            for (int s = 0; s < 4; ++s) {
                float f0, f1, f2, f3, f4, f5, f6, f7;
                dec4(kv[s].x, f0, f1, f2, f3);
                dec4(kv[s].y, f4, f5, f6, f7);
                d0 = fmaf(f0, v[s][0], d0); d1 = fmaf(f1, v[s][1], d1);
                d2 = fmaf(f2, v[s][2], d2); d3 = fmaf(f3, v[s][3], d3);
                d4 = fmaf(f4, v[s][4], d4); d5 = fmaf(f5, v[s][5], d5);
                d6 = fmaf(f6, v[s][6], d6); d7 = fmaf(f7, v[s][7], d7);
            }
            float d = ((d0 + d1) + (d2 + d3)) + ((d4 + d5) + (d6 + d7));
#pragma unroll
            for (int off = 32; off > 0; off >>= 1) d += __shfl_xor(d, off, 64);
            u = INV_N * fastrcp(d * invs + 1e-8f);
        }
        const float uw = u * invs;
        if (l == 0) u_out[b * NN + row0 + r] = uw;

#pragma unroll
        for (int s = 0; s < 4; ++s) {
            float f0, f1, f2, f3, f4, f5, f6, f7;
            dec4(kv[s].x, f0, f1, f2, f3);
            dec4(kv[s].y, f4, f5, f6, f7);
            acc[s][0] = fmaf(f0, uw, acc[s][0]); acc[s][1] = fmaf(f1, uw, acc[s][1]);
            acc[s][2] = fmaf(f2, uw, acc[s][2]); acc[s][3] = fmaf(f3, uw, acc[s][3]);
            acc[s][4] = fmaf(f4, uw, acc[s][4]); acc[s][5] = fmaf(f5, uw, acc[s][5]);
            acc[s][6] = fmaf(f6, uw, acc[s][6]); acc[s][7] = fmaf(f7, uw, acc[s][7]);
        }
    }

    // fold 4 waves' column partials via LDS, one store per block
    __shared__ float lds[4][NN];                            // 32 KB
#pragma unroll
    for (int s = 0; s < 4; ++s) {
        *(float4*)&lds[w][s * 512 + l * 8]     = make_float4(acc[s][0], acc[s][1], acc[s][2], acc[s][3]);
        *(float4*)&lds[w][s * 512 + l * 8 + 4] = make_float4(acc[s][4], acc[s][5], acc[s][6], acc[s][7]);
    }
    __syncthreads();
    float o[8];
#pragma unroll
    for (int j = 0; j < 8; ++j)
        o[j] = (lds[0][tid * 8 + j] + lds[1][tid * 8 + j]) +
               (lds[2][tid * 8 + j] + lds[3][tid * 8 + j]);
    float* p = PART + ((size_t)(b * G + g)) * NN + tid * 8;
    *(float4*)(p)     = make_float4(o[0], o[1], o[2], o[3]);
    *(float4*)(p + 4) = make_float4(o[4], o[5], o[6], o[7]);
}

// ------------------------------------------------- final: sum uw[n]*K8[n,m]*C[n,m]*v[m] / B
__global__ __launch_bounds__(256) void final_sum(const unsigned char* __restrict__ K8,
                                                 const float* __restrict__ x,
                                                 const float* __restrict__ y,
                                                 const float* __restrict__ VV,
                                                 const float* __restrict__ u_in,   // holds uw = u*invs
                                                 float* __restrict__ out) {
    const int g = blockIdx.x, b = blockIdx.y, tid = threadIdx.x;
    const int w = tid >> 6, l = tid & 63;
    const float* vb = VV + b * NN;

    float v[4][8];
#pragma unroll
    for (int s = 0; s < 4; ++s) {
        const float4 p0 = *(const float4*)(vb + s * 512 + l * 8);
        const float4 p1 = *(const float4*)(vb + s * 512 + l * 8 + 4);
        v[s][0] = p0.x; v[s][1] = p0.y; v[s][2] = p0.z; v[s][3] = p0.w;
        v[s][4] = p1.x; v[s][5] = p1.y; v[s][6] = p1.z; v[s][7] = p1.w;
    }

    const float* xb = x + (size_t)b * 3 * NN;
    const float* yb = y + (size_t)b * 3 * NN;
    float lacc = 0.0f;

    for (int r = 0; r < 8; ++r) {
        const int n = g * 32 + w * 8 + r;
        const float x0 = xb[n], x1 = xb[NN + n], x2 = xb[2 * NN + n];
        const float xs = x0 * x0 + x1 * x1 + x2 * x2;
        const float uwn = u_in[b * NN + n];
        const unsigned char* Kp = K8 + ((size_t)(b * NN + n)) * NN + l * 8;
        float racc = 0.0f;
#pragma unroll
        for (int s = 0; s < 4; ++s) {
            const int m0 = s * 512 + l * 8;
            const uint2 kv = *(const uint2*)(Kp + s * 512);
            float ky[8];
            dec4(kv.x, ky[0], ky[1], ky[2], ky[3]);
            dec4(kv.y, ky[4], ky[5], ky[6], ky[7]);
            const float4 a0 = *(const float4*)(yb + m0);
            const float4 a1 = *(const float4*)(yb + m0 + 4);
            const float4 b0 = *(const float4*)(yb + NN + m0);
            const float4 b1 = *(const float4*)(yb + NN + m0 + 4);
            const float4 c0 = *(const float4*)(yb + 2 * NN + m0);
            const float4 c1 = *(const float4*)(yb + 2 * NN + m0 + 4);
            const float yy0[8] = {a0.x, a0.y, a0.z, a0.w, a1.x, a1.y, a1.z, a1.w};
            const float yy1[8] = {b0.x, b0.y, b0.z, b0.w, b1.x, b1.y, b1.z, b1.w};
            const float yy2[8] = {c0.x, c0.y, c0.z, c0.w, c1.x, c1.y, c1.z, c1.w};
#pragma unroll
            for (int j = 0; j < 8; ++j) {
                const float ys  = yy0[j] * yy0[j] + yy1[j] * yy1[j] + yy2[j] * yy2[j];
                const float dot = x0 * yy0[j] + x1 * yy1[j] + x2 * yy2[j];
                const float C   = fmaxf(xs + ys - 2.0f * dot, 0.0f);
                racc = fmaf(ky[j] * C, v[s][j], racc);
            }
        }
        lacc = fmaf(uwn, racc, lacc);   // uwn uniform per row: defer lane-reduction
    }
#pragma unroll
    for (int off = 32; off > 0; off >>= 1) lacc += __shfl_xor(lacc, off, 64);
    __shared__ float red[4];
    if (l == 0) red[w] = lacc;
    __syncthreads();
    if (tid == 0) atomicAdd(out, (red[0] + red[1] + red[2] + red[3]) * (1.0f / (float)NB));
}

extern "C" void kernel_launch(void* const* d_in, const int* in_sizes, int n_in,
                              void* d_out, int out_size, void* d_ws, size_t ws_size,
                              hipStream_t stream) {
    const float* x = (const float*)d_in[0];
    const float* y = (const float*)d_in[1];
    float* out = (float*)d_out;
    char* ws = (char*)d_ws;

    unsigned char* K8 = (unsigned char*)ws;                  // 16*2048*2048 = 67,108,864 B
    const size_t KBYTES = (size_t)NB * NN * NN;
    float* PART = (float*)(ws + KBYTES);                     // 16*64*2048*4 = 8 MiB
    const size_t PARTN = (size_t)NB * G * NN;
    float* VV   = PART + PARTN;                              // v vector, 128 KiB
    float* ub   = VV + (size_t)NB * NN;                      // uw vector, 128 KiB
    float* INVS = ub + (size_t)NB * NN;                      // per-row 1/scale, 128 KiB

    hipMemsetAsync(out, 0, sizeof(float), stream);

    build_K<<<dim3(NN, NB), 256, 0, stream>>>(x, y, K8, INVS);

    // iteration 0 half-step: PART <- K^T u0 (u0 = inv_n), phase A skipped
    fused_pass<<<dim3(G, NB), 256, 0, stream>>>(K8, VV, INVS, ub, PART, 1);
    for (int i = 0; i < ITERS; ++i) {
        reduce_v<<<dim3(NB * NN / 256), 256, 0, stream>>>(PART, VV);               // v_k
        fused_pass<<<dim3(G, NB), 256, 0, stream>>>(K8, VV, INVS, ub, PART, 0);    // u_k, PART
    }
    // ub = uw_100, VV = v_100
    final_sum<<<dim3(G, NB), 256, 0, stream>>>(K8, x, y, VV, ub, out);
}